// Round 1
// baseline (652.783 us; speedup 1.0000x reference)
//
#include <hip/hip_runtime.h>

#define B_SZ   2
#define S_LEN  2048
#define D_DIM  1024
#define V_DIM  32000
#define NTOK   (B_SZ * S_LEN)   // 4096
#define NCYC   8
#define NPLANES 256
#define EPS_F  1.1920929e-07f

typedef float  f32x4  __attribute__((ext_vector_type(4)));
typedef __bf16 bf16x8 __attribute__((ext_vector_type(8)));

__device__ __forceinline__ unsigned short f32_to_bf16(float f) {
    unsigned int u = __builtin_bit_cast(unsigned int, f);
    u += 0x7fffu + ((u >> 16) & 1u);   // round-to-nearest-even
    return (unsigned short)(u >> 16);
}

__device__ __forceinline__ float block_reduce_sum(float v, float* red) {
    const int tid = threadIdx.x;
    #pragma unroll
    for (int off = 32; off > 0; off >>= 1) v += __shfl_down(v, off, 64);
    if ((tid & 63) == 0) red[tid >> 6] = v;
    __syncthreads();
    return red[0] + red[1] + red[2] + red[3];
}

// ---------------- embed gather: x[t,:] = table[tokens[t],:] ----------------
__global__ __launch_bounds__(256) void k_embed(const int* __restrict__ tokens,
                                               const float* __restrict__ table,
                                               float* __restrict__ x) {
    const int t = blockIdx.x;
    const int tok = tokens[t];
    const float4* src = (const float4*)(table + (size_t)tok * D_DIM);
    float4* dst = (float4*)(x + (size_t)t * D_DIM);
    dst[threadIdx.x] = src[threadIdx.x];
}

// ---------------- one cycle: mix -> rotate -> silu -> rmsnorm residual -----
__global__ __launch_bounds__(256) void k_cycle(
    const float* __restrict__ xin, float* __restrict__ xout,
    const float* __restrict__ angles, const float* __restrict__ scales,
    const float* __restrict__ shifts, const float* __restrict__ normw,
    const float* __restrict__ mixw, const int* __restrict__ pi,
    const int* __restrict__ pj)
{
    __shared__ float lx[D_DIM];
    __shared__ float red[4];
    const int t = blockIdx.x;
    const int s = t & (S_LEN - 1);
    const int tid = threadIdx.x;
    const int d0 = tid * 4;

    float4 sv = ((const float4*)(xin + (size_t)t * D_DIM))[tid];
    float4 lv = make_float4(0.f, 0.f, 0.f, 0.f);
    float4 rv = make_float4(0.f, 0.f, 0.f, 0.f);
    if (s > 0)         lv = ((const float4*)(xin + (size_t)(t - 1) * D_DIM))[tid];
    if (s < S_LEN - 1) rv = ((const float4*)(xin + (size_t)(t + 1) * D_DIM))[tid];
    const float mw0 = mixw[0], mw1 = mixw[1], mw2 = mixw[2];

    const float m0 = mw0 * lv.x + mw1 * sv.x + mw2 * rv.x;
    const float m1 = mw0 * lv.y + mw1 * sv.y + mw2 * rv.y;
    const float m2 = mw0 * lv.z + mw1 * sv.z + mw2 * rv.z;
    const float m3 = mw0 * lv.w + mw1 * sv.w + mw2 * rv.w;
    lx[d0 + 0] = m0; lx[d0 + 1] = m1; lx[d0 + 2] = m2; lx[d0 + 3] = m3;
    __syncthreads();

    // Givens rotation: one plane per thread (P == 256 == blockDim)
    const int ip = pi[tid], jp = pj[tid];
    float sa, ca;
    sincosf(angles[tid], &sa, &ca);
    const float xi = lx[ip], xj = lx[jp];
    __syncthreads();
    lx[ip] = xi * ca - xj * sa;
    lx[jp] = xi * sa + xj * ca;
    __syncthreads();

    const float4 sc = ((const float4*)scales)[tid];
    const float4 sh = ((const float4*)shifts)[tid];
    const float4 nw = ((const float4*)normw)[tid];
    const float xn0 = lx[d0 + 0], xn1 = lx[d0 + 1], xn2 = lx[d0 + 2], xn3 = lx[d0 + 3];
    const float a0 = xn0 * sc.x + sh.x;
    const float a1 = xn1 * sc.y + sh.y;
    const float a2 = xn2 * sc.z + sh.z;
    const float a3 = xn3 * sc.w + sh.w;
    const float r0 = a0 / (1.f + expf(-a0)) - m0;
    const float r1 = a1 / (1.f + expf(-a1)) - m1;
    const float r2 = a2 / (1.f + expf(-a2)) - m2;
    const float r3 = a3 / (1.f + expf(-a3)) - m3;

    const float tot = block_reduce_sum(r0 * r0 + r1 * r1 + r2 * r2 + r3 * r3, red);
    const float inv = rsqrtf(tot * (1.0f / D_DIM) + EPS_F);

    float4 o;
    o.x = m0 + r0 * inv * nw.x;
    o.y = m1 + r1 * inv * nw.y;
    o.z = m2 + r2 * inv * nw.z;
    o.w = m3 + r3 * inv * nw.w;
    ((float4*)(xout + (size_t)t * D_DIM))[tid] = o;
}

// ---------------- final rmsnorm + cast to bf16 -----------------------------
__global__ __launch_bounds__(256) void k_final(const float* __restrict__ xin,
                                               const float* __restrict__ ow,
                                               unsigned short* __restrict__ xb)
{
    __shared__ float red[4];
    const int t = blockIdx.x, tid = threadIdx.x;
    const float4 v = ((const float4*)(xin + (size_t)t * D_DIM))[tid];
    const float tot = block_reduce_sum(v.x * v.x + v.y * v.y + v.z * v.z + v.w * v.w, red);
    const float inv = rsqrtf(tot * (1.0f / D_DIM) + EPS_F);
    const float4 w = ((const float4*)ow)[tid];
    ushort4 o = make_ushort4(f32_to_bf16(v.x * inv * w.x),
                             f32_to_bf16(v.y * inv * w.y),
                             f32_to_bf16(v.z * inv * w.z),
                             f32_to_bf16(v.w * inv * w.w));
    ((ushort4*)xb)[(size_t)t * 256 + tid] = o;
}

// ---------------- lm_head fp32 -> bf16 -------------------------------------
__global__ __launch_bounds__(256) void k_cvt(const float* __restrict__ w,
                                             unsigned short* __restrict__ wb, int n4)
{
    int i = blockIdx.x * 256 + threadIdx.x;
    const int stride = gridDim.x * 256;
    for (; i < n4; i += stride) {
        const float4 v = ((const float4*)w)[i];
        ushort4 o = make_ushort4(f32_to_bf16(v.x), f32_to_bf16(v.y),
                                 f32_to_bf16(v.z), f32_to_bf16(v.w));
        ((ushort4*)wb)[i] = o;
    }
}

// ---------------- GEMM: C[M,N] = A[M,K] * B[N,K]^T, bf16 MFMA --------------
// m97 structure: 128x128 tile, BK=32, 4 waves (2x2), 4x4 16x16x32 frags/wave,
// global_load_lds width-16 staging, single-buffered LDS, 2 barriers/K-step.
#define GLD_LDS(g, l)                                                          \
    __builtin_amdgcn_global_load_lds(                                          \
        (const __attribute__((address_space(1))) void*)(g),                    \
        (__attribute__((address_space(3))) void*)(l), 16, 0, 0)

__global__ __launch_bounds__(256) void k_gemm(
    const unsigned short* __restrict__ A,   // [NTOK, D] bf16 bits
    const unsigned short* __restrict__ Bw,  // [V, D]    bf16 bits
    float* __restrict__ C)                  // [NTOK, V] fp32
{
    constexpr int K = D_DIM;
    __shared__ __align__(16) unsigned short lA[128 * 32];
    __shared__ __align__(16) unsigned short lB[128 * 32];
    const int tid = threadIdx.x;
    const int wave = tid >> 6, lane = tid & 63;
    const int nbn = V_DIM / 128;  // 250
    const int bm = blockIdx.x / nbn, bn = blockIdx.x % nbn;
    const int wm = wave >> 1, wn = wave & 1;
    const int lrow = lane & 15, kgrp = lane >> 4;

    // staging addressing: each wave stages 32 rows (2 calls x 16 rows x 64B)
    const int srow = lane >> 2;          // 0..15
    const int scol = (lane & 3) * 8;     // ushort offset within row
    const unsigned short* gA0 = A  + (size_t)(bm * 128 + wave * 32 + srow) * K + scol;
    const unsigned short* gA1 = gA0 + (size_t)16 * K;
    const unsigned short* gB0 = Bw + (size_t)(bn * 128 + wave * 32 + srow) * K + scol;
    const unsigned short* gB1 = gB0 + (size_t)16 * K;
    unsigned short* lA0 = lA + (wave * 32) * 32;
    unsigned short* lA1 = lA0 + 16 * 32;
    unsigned short* lB0 = lB + (wave * 32) * 32;
    unsigned short* lB1 = lB0 + 16 * 32;

    f32x4 acc[4][4];
    #pragma unroll
    for (int i = 0; i < 4; i++)
        #pragma unroll
        for (int j = 0; j < 4; j++) acc[i][j] = (f32x4){0.f, 0.f, 0.f, 0.f};

    for (int k0 = 0; k0 < K; k0 += 32) {
        GLD_LDS(gA0 + k0, lA0);
        GLD_LDS(gA1 + k0, lA1);
        GLD_LDS(gB0 + k0, lB0);
        GLD_LDS(gB1 + k0, lB1);
        __syncthreads();   // drains vmcnt before barrier (compiler-inserted)

        bf16x8 af[4], bfr[4];
        #pragma unroll
        for (int mi = 0; mi < 4; mi++)
            af[mi] = *(const bf16x8*)&lA[(wm * 64 + mi * 16 + lrow) * 32 + kgrp * 8];
        #pragma unroll
        for (int ni = 0; ni < 4; ni++)
            bfr[ni] = *(const bf16x8*)&lB[(wn * 64 + ni * 16 + lrow) * 32 + kgrp * 8];
        #pragma unroll
        for (int mi = 0; mi < 4; mi++)
            #pragma unroll
            for (int ni = 0; ni < 4; ni++)
                acc[mi][ni] = __builtin_amdgcn_mfma_f32_16x16x32_bf16(
                    af[mi], bfr[ni], acc[mi][ni], 0, 0, 0);
        __syncthreads();
    }

    // epilogue: C[m][n], m = (lane>>4)*4 + reg, n = lane&15 (verified mapping)
    #pragma unroll
    for (int mi = 0; mi < 4; mi++) {
        const int m0 = bm * 128 + wm * 64 + mi * 16 + kgrp * 4;
        #pragma unroll
        for (int ni = 0; ni < 4; ni++) {
            const int n = bn * 128 + wn * 64 + ni * 16 + lrow;
            float* cp = C + (size_t)m0 * V_DIM + n;
            cp[0]                   = acc[mi][ni][0];
            cp[(size_t)V_DIM]       = acc[mi][ni][1];
            cp[(size_t)2 * V_DIM]   = acc[mi][ni][2];
            cp[(size_t)3 * V_DIM]   = acc[mi][ni][3];
        }
    }
}

extern "C" void kernel_launch(void* const* d_in, const int* in_sizes, int n_in,
                              void* d_out, int out_size, void* d_ws, size_t ws_size,
                              hipStream_t stream)
{
    const int*   tokens = (const int*)  d_in[0];
    const float* embedw = (const float*)d_in[1];
    const float* angles = (const float*)d_in[2];
    const float* scales = (const float*)d_in[3];
    const float* shifts = (const float*)d_in[4];
    const float* normw  = (const float*)d_in[5];
    const float* mixw   = (const float*)d_in[6];
    const float* outnw  = (const float*)d_in[7];
    const float* lmhead = (const float*)d_in[8];
    const int*   pi_all = (const int*)  d_in[9];
    const int*   pj_all = (const int*)  d_in[10];
    float* out = (float*)d_out;

    // workspace layout (~107.5 MB total)
    float* xa = (float*)d_ws;                                  // 16.78 MB
    float* xb = xa + (size_t)NTOK * D_DIM;                     // 16.78 MB
    unsigned short* xbf = (unsigned short*)(xb + (size_t)NTOK * D_DIM); // 8.39 MB
    unsigned short* wbf = xbf + (size_t)NTOK * D_DIM;          // 65.54 MB

    k_embed<<<NTOK, 256, 0, stream>>>(tokens, embedw, xa);

    const float* cin = xa;
    float* cout = xb;
    for (int c = 0; c < NCYC; ++c) {
        k_cycle<<<NTOK, 256, 0, stream>>>(cin, cout,
            angles + c * NPLANES, scales + c * D_DIM, shifts + c * D_DIM,
            normw + c * D_DIM, mixw, pi_all + c * NPLANES, pj_all + c * NPLANES);
        float* tmp = (float*)cin; cin = cout; cout = tmp;
    }
    // after 8 cycles (even count) result is back in xa (== cin)

    k_final<<<NTOK, 256, 0, stream>>>(cin, outnw, xbf);
    k_cvt<<<2048, 256, 0, stream>>>(lmhead, wbf, (V_DIM * D_DIM) / 4);
    k_gemm<<<32 * 250, 256, 0, stream>>>(xbf, wbf, out);
}

// Round 2
// 466.165 us; speedup vs baseline: 1.4003x; 1.4003x over previous
//
#include <hip/hip_runtime.h>

#define B_SZ   2
#define S_LEN  2048
#define D_DIM  1024
#define V_DIM  32000
#define NTOK   (B_SZ * S_LEN)   // 4096
#define NCYC   8
#define NPLANES 256
#define EPS_F  1.1920929e-07f

typedef float  f32x4  __attribute__((ext_vector_type(4)));
typedef __bf16 bf16x8 __attribute__((ext_vector_type(8)));

__device__ __forceinline__ unsigned short f32_to_bf16(float f) {
    unsigned int u = __builtin_bit_cast(unsigned int, f);
    u += 0x7fffu + ((u >> 16) & 1u);   // round-to-nearest-even
    return (unsigned short)(u >> 16);
}

__device__ __forceinline__ float block_reduce_sum(float v, float* red) {
    const int tid = threadIdx.x;
    #pragma unroll
    for (int off = 32; off > 0; off >>= 1) v += __shfl_down(v, off, 64);
    if ((tid & 63) == 0) red[tid >> 6] = v;
    __syncthreads();
    return red[0] + red[1] + red[2] + red[3];
}

// ---------------- embed gather ----------------
__global__ __launch_bounds__(256) void k_embed(const int* __restrict__ tokens,
                                               const float* __restrict__ table,
                                               float* __restrict__ x) {
    const int t = blockIdx.x;
    const int tok = tokens[t];
    const float4* src = (const float4*)(table + (size_t)tok * D_DIM);
    float4* dst = (float4*)(x + (size_t)t * D_DIM);
    dst[threadIdx.x] = src[threadIdx.x];
}

// ---------------- one cycle ----------------
__global__ __launch_bounds__(256) void k_cycle(
    const float* __restrict__ xin, float* __restrict__ xout,
    const float* __restrict__ angles, const float* __restrict__ scales,
    const float* __restrict__ shifts, const float* __restrict__ normw,
    const float* __restrict__ mixw, const int* __restrict__ pi,
    const int* __restrict__ pj)
{
    __shared__ float lx[D_DIM];
    __shared__ float red[4];
    const int t = blockIdx.x;
    const int s = t & (S_LEN - 1);
    const int tid = threadIdx.x;
    const int d0 = tid * 4;

    float4 sv = ((const float4*)(xin + (size_t)t * D_DIM))[tid];
    float4 lv = make_float4(0.f, 0.f, 0.f, 0.f);
    float4 rv = make_float4(0.f, 0.f, 0.f, 0.f);
    if (s > 0)         lv = ((const float4*)(xin + (size_t)(t - 1) * D_DIM))[tid];
    if (s < S_LEN - 1) rv = ((const float4*)(xin + (size_t)(t + 1) * D_DIM))[tid];
    const float mw0 = mixw[0], mw1 = mixw[1], mw2 = mixw[2];

    const float m0 = mw0 * lv.x + mw1 * sv.x + mw2 * rv.x;
    const float m1 = mw0 * lv.y + mw1 * sv.y + mw2 * rv.y;
    const float m2 = mw0 * lv.z + mw1 * sv.z + mw2 * rv.z;
    const float m3 = mw0 * lv.w + mw1 * sv.w + mw2 * rv.w;
    lx[d0 + 0] = m0; lx[d0 + 1] = m1; lx[d0 + 2] = m2; lx[d0 + 3] = m3;
    __syncthreads();

    const int ip = pi[tid], jp = pj[tid];
    float sa, ca;
    sincosf(angles[tid], &sa, &ca);
    const float xi = lx[ip], xj = lx[jp];
    __syncthreads();
    lx[ip] = xi * ca - xj * sa;
    lx[jp] = xi * sa + xj * ca;
    __syncthreads();

    const float4 sc = ((const float4*)scales)[tid];
    const float4 sh = ((const float4*)shifts)[tid];
    const float4 nw = ((const float4*)normw)[tid];
    const float xn0 = lx[d0 + 0], xn1 = lx[d0 + 1], xn2 = lx[d0 + 2], xn3 = lx[d0 + 3];
    const float a0 = xn0 * sc.x + sh.x;
    const float a1 = xn1 * sc.y + sh.y;
    const float a2 = xn2 * sc.z + sh.z;
    const float a3 = xn3 * sc.w + sh.w;
    const float r0 = a0 / (1.f + expf(-a0)) - m0;
    const float r1 = a1 / (1.f + expf(-a1)) - m1;
    const float r2 = a2 / (1.f + expf(-a2)) - m2;
    const float r3 = a3 / (1.f + expf(-a3)) - m3;

    const float tot = block_reduce_sum(r0 * r0 + r1 * r1 + r2 * r2 + r3 * r3, red);
    const float inv = rsqrtf(tot * (1.0f / D_DIM) + EPS_F);

    float4 o;
    o.x = m0 + r0 * inv * nw.x;
    o.y = m1 + r1 * inv * nw.y;
    o.z = m2 + r2 * inv * nw.z;
    o.w = m3 + r3 * inv * nw.w;
    ((float4*)(xout + (size_t)t * D_DIM))[tid] = o;
}

// ---------------- final rmsnorm + cast to bf16 ----------------
__global__ __launch_bounds__(256) void k_final(const float* __restrict__ xin,
                                               const float* __restrict__ ow,
                                               unsigned short* __restrict__ xb)
{
    __shared__ float red[4];
    const int t = blockIdx.x, tid = threadIdx.x;
    const float4 v = ((const float4*)(xin + (size_t)t * D_DIM))[tid];
    const float tot = block_reduce_sum(v.x * v.x + v.y * v.y + v.z * v.z + v.w * v.w, red);
    const float inv = rsqrtf(tot * (1.0f / D_DIM) + EPS_F);
    const float4 w = ((const float4*)ow)[tid];
    ushort4 o = make_ushort4(f32_to_bf16(v.x * inv * w.x),
                             f32_to_bf16(v.y * inv * w.y),
                             f32_to_bf16(v.z * inv * w.z),
                             f32_to_bf16(v.w * inv * w.w));
    ((ushort4*)xb)[(size_t)t * 256 + tid] = o;
}

// ---------------- lm_head fp32 -> bf16 ----------------
__global__ __launch_bounds__(256) void k_cvt(const float* __restrict__ w,
                                             unsigned short* __restrict__ wb, int n4)
{
    int i = blockIdx.x * 256 + threadIdx.x;
    const int stride = gridDim.x * 256;
    for (; i < n4; i += stride) {
        const float4 v = ((const float4*)w)[i];
        ushort4 o = make_ushort4(f32_to_bf16(v.x), f32_to_bf16(v.y),
                                 f32_to_bf16(v.z), f32_to_bf16(v.w));
        ((ushort4*)wb)[i] = o;
    }
}

// ================= GEMM: 256x256 tile, BK=64, 8-phase schedule =============
// C[M,N] = A[M,K] * B[N,K]^T, bf16 MFMA 16x16x32, fp32 out.
// 8 waves (2M x 4N), per-wave 128x64 out = acc[8][4] f32x4.
// LDS 128 KiB: 2 bufs x (A 256x64 + B 256x64) bf16, XOR-swizzled
// (elem col ^= (row&7)*8; global source pre-swizzled for global_load_lds).
// Per iteration: 2 K-tiles, 8 phases; counted vmcnt(4) at phases 4 & 8.
#define GLD_LDS(g, l)                                                          \
    __builtin_amdgcn_global_load_lds(                                          \
        (const __attribute__((address_space(1))) void*)(g),                    \
        (__attribute__((address_space(3))) void*)(l), 16, 0, 0)

#define STAGE_A(BUF, H, KT) do {                                               \
    GLD_LDS(gA + (size_t)(H) * 131072 + (size_t)(KT) * 64,                     \
            &lds[(BUF) * 32768 + (H) * 8192 + wave * 1024]);                   \
    GLD_LDS(gA + (size_t)(H) * 131072 + 8192 + (size_t)(KT) * 64,              \
            &lds[(BUF) * 32768 + (H) * 8192 + wave * 1024 + 512]);             \
} while (0)

#define STAGE_B(BUF, H, KT) do {                                               \
    GLD_LDS(gB + (size_t)(H) * 131072 + (size_t)(KT) * 64,                     \
            &lds[16384 + (BUF) * 32768 + (H) * 8192 + wave * 1024]);           \
    GLD_LDS(gB + (size_t)(H) * 131072 + 8192 + (size_t)(KT) * 64,              \
            &lds[16384 + (BUF) * 32768 + (H) * 8192 + wave * 1024 + 512]);     \
} while (0)

#define RD_A(BUF, MIB) do { _Pragma("unroll")                                  \
    for (int q_ = 0; q_ < 4; ++q_) {                                           \
        afr[q_][0] = *(const bf16x8*)&lds[(BUF) * 32768 + aoff + ((MIB) + q_) * 1024 + kx0]; \
        afr[q_][1] = *(const bf16x8*)&lds[(BUF) * 32768 + aoff + ((MIB) + q_) * 1024 + kx1]; \
    } } while (0)

#define RD_B(BUF, NIB, DST) do { _Pragma("unroll")                             \
    for (int n_ = 0; n_ < 2; ++n_) {                                           \
        DST[n_][0] = *(const bf16x8*)&lds[(BUF) * 32768 + boff + ((NIB) + n_) * 1024 + kx0]; \
        DST[n_][1] = *(const bf16x8*)&lds[(BUF) * 32768 + boff + ((NIB) + n_) * 1024 + kx1]; \
    } } while (0)

#define MFMA16(MIB, NIB, BF) do {                                              \
    __builtin_amdgcn_s_setprio(1);                                             \
    _Pragma("unroll") for (int m_ = 0; m_ < 4; ++m_)                           \
    _Pragma("unroll") for (int n_ = 0; n_ < 2; ++n_) {                         \
        acc[(MIB) + m_][(NIB) + n_] = __builtin_amdgcn_mfma_f32_16x16x32_bf16( \
            afr[m_][0], BF[n_][0], acc[(MIB) + m_][(NIB) + n_], 0, 0, 0);      \
        acc[(MIB) + m_][(NIB) + n_] = __builtin_amdgcn_mfma_f32_16x16x32_bf16( \
            afr[m_][1], BF[n_][1], acc[(MIB) + m_][(NIB) + n_], 0, 0, 0);      \
    }                                                                          \
    __builtin_amdgcn_s_setprio(0); } while (0)

#define PH_SYNC() do { __builtin_amdgcn_s_barrier();                           \
    asm volatile("s_waitcnt lgkmcnt(0)" ::: "memory"); } while (0)
#define PH_END() do { asm volatile("" ::: "memory");                           \
    __builtin_amdgcn_s_barrier(); } while (0)
#define VMCNT4() asm volatile("s_waitcnt vmcnt(4)" ::: "memory")

__global__ __launch_bounds__(512, 2) void k_gemm(
    const unsigned short* __restrict__ A,   // [NTOK, 1024] bf16 bits
    const unsigned short* __restrict__ Bw,  // [V, 1024]    bf16 bits
    float* __restrict__ C)                  // [NTOK, V]    fp32
{
    __shared__ __align__(16) unsigned short lds[65536];   // 128 KiB
    const int tid = threadIdx.x;
    const int wave = tid >> 6, lane = tid & 63;
    const int wm = wave >> 2, wn = wave & 3;
    const int lr = lane & 15, kg = lane >> 4;

    // XCD-aware swizzle: 2000 wgs, 2000 % 8 == 0 -> simple form is bijective
    const int swz = (blockIdx.x & 7) * 250 + (blockIdx.x >> 3);
    const int bm = swz / 125, bn = swz % 125;

    // swizzled frag-read column offsets (elements within a 64-elem row)
    const int xr  = (lane & 7) * 8;
    const int kx0 = (kg * 8) ^ xr;
    const int kx1 = (32 + kg * 8) ^ xr;
    const int aoff = (wm * 128 + lr) * 64;           // A region at LDS offset 0
    const int boff = 16384 + (wn * 64 + lr) * 64;    // B region at +16384 elems

    // staging: wave w covers rows w*16..w*16+15 of each 128-row half-tile;
    // global source col pre-swizzled so linear global_load_lds dest matches.
    const int srow = lane >> 3;                      // 0..7
    const int scol = ((lane & 7) ^ srow) * 8;        // pre-swizzled col (elems)
    const unsigned short* gA = A  + (size_t)(bm * 256 + wave * 16 + srow) * 1024 + scol;
    const unsigned short* gB = Bw + (size_t)(bn * 256 + wave * 16 + srow) * 1024 + scol;

    f32x4 acc[8][4];
    #pragma unroll
    for (int i = 0; i < 8; ++i)
        #pragma unroll
        for (int j = 0; j < 4; ++j) acc[i][j] = (f32x4){0.f, 0.f, 0.f, 0.f};
    bf16x8 afr[4][2], b01[2][2], b23[2][2];

    // prologue: buf0 <- K-tile 0 (A+B), buf1 <- K-tile 1 (B only; A(1) staged
    // by iter 0 ph1/ph2). vmcnt(4) drains buf0's 8 loads, leaves B1's 4.
    STAGE_A(0, 0, 0); STAGE_A(0, 1, 0);
    STAGE_B(0, 0, 0); STAGE_B(0, 1, 0);
    STAGE_B(1, 0, 1); STAGE_B(1, 1, 1);
    VMCNT4();
    __builtin_amdgcn_s_barrier();

    for (int j = 0; j < 8; ++j) {
        const int k1 = (2 * j + 1) & 15;   // A -> buf1 (this iter's 2nd K-tile)
        const int k2 = (2 * j + 2) & 15;   // next K-tile -> buf0
        const int k3 = (2 * j + 3) & 15;   // B of K-tile after -> buf1
        // ---- phases 1-4: compute buf0 (K-tile 2j) ----
        RD_A(0, 0); RD_B(0, 0, b01);
        STAGE_A(1, 0, k1);
        PH_SYNC(); MFMA16(0, 0, b01); PH_END();

        RD_B(0, 2, b23);
        STAGE_A(1, 1, k1);
        PH_SYNC(); MFMA16(0, 2, b23); PH_END();

        RD_A(0, 4);
        STAGE_B(0, 0, k2);
        PH_SYNC(); MFMA16(4, 2, b23); PH_END();

        STAGE_B(0, 1, k2);
        VMCNT4();
        PH_SYNC(); MFMA16(4, 0, b01); PH_END();
        // ---- phases 5-8: compute buf1 (K-tile 2j+1) ----
        RD_A(1, 0); RD_B(1, 0, b01);
        STAGE_A(0, 0, k2);
        PH_SYNC(); MFMA16(0, 0, b01); PH_END();

        RD_B(1, 2, b23);
        STAGE_A(0, 1, k2);
        PH_SYNC(); MFMA16(0, 2, b23); PH_END();

        RD_A(1, 4);
        STAGE_B(1, 0, k3);
        PH_SYNC(); MFMA16(4, 2, b23); PH_END();

        STAGE_B(1, 1, k3);
        VMCNT4();
        PH_SYNC(); MFMA16(4, 0, b01); PH_END();
    }

    // epilogue: C row = base + mi*16 + kg*4 + reg, col = base + ni*16 + lr
    #pragma unroll
    for (int mi = 0; mi < 8; ++mi) {
        const size_t m0 = (size_t)(bm * 256 + wm * 128 + mi * 16 + kg * 4);
        #pragma unroll
        for (int ni = 0; ni < 4; ++ni) {
            const int n = bn * 256 + wn * 64 + ni * 16 + lr;
            float* cp = C + m0 * V_DIM + n;
            cp[0]                 = acc[mi][ni][0];
            cp[(size_t)V_DIM]     = acc[mi][ni][1];
            cp[(size_t)2 * V_DIM] = acc[mi][ni][2];
            cp[(size_t)3 * V_DIM] = acc[mi][ni][3];
        }
    }
}

extern "C" void kernel_launch(void* const* d_in, const int* in_sizes, int n_in,
                              void* d_out, int out_size, void* d_ws, size_t ws_size,
                              hipStream_t stream)
{
    const int*   tokens = (const int*)  d_in[0];
    const float* embedw = (const float*)d_in[1];
    const float* angles = (const float*)d_in[2];
    const float* scales = (const float*)d_in[3];
    const float* shifts = (const float*)d_in[4];
    const float* normw  = (const float*)d_in[5];
    const float* mixw   = (const float*)d_in[6];
    const float* outnw  = (const float*)d_in[7];
    const float* lmhead = (const float*)d_in[8];
    const int*   pi_all = (const int*)  d_in[9];
    const int*   pj_all = (const int*)  d_in[10];
    float* out = (float*)d_out;

    float* xa = (float*)d_ws;
    float* xb = xa + (size_t)NTOK * D_DIM;
    unsigned short* xbf = (unsigned short*)(xb + (size_t)NTOK * D_DIM);
    unsigned short* wbf = xbf + (size_t)NTOK * D_DIM;

    k_embed<<<NTOK, 256, 0, stream>>>(tokens, embedw, xa);

    const float* cin = xa;
    float* cout = xb;
    for (int c = 0; c < NCYC; ++c) {
        k_cycle<<<NTOK, 256, 0, stream>>>(cin, cout,
            angles + c * NPLANES, scales + c * D_DIM, shifts + c * D_DIM,
            normw + c * D_DIM, mixw, pi_all + c * NPLANES, pj_all + c * NPLANES);
        float* tmp = (float*)cin; cin = cout; cout = tmp;
    }

    k_final<<<NTOK, 256, 0, stream>>>(cin, outnw, xbf);
    k_cvt<<<2048, 256, 0, stream>>>(lmhead, wbf, (V_DIM * D_DIM) / 4);
    k_gemm<<<16 * 125, 512, 0, stream>>>(xbf, wbf, out);
}

// Round 4
// 425.788 us; speedup vs baseline: 1.5331x; 1.0948x over previous
//
#include <hip/hip_runtime.h>

#define B_SZ   2
#define S_LEN  2048
#define D_DIM  1024
#define V_DIM  32000
#define NTOK   (B_SZ * S_LEN)   // 4096
#define NCYC   8
#define NPLANES 256
#define EPS_F  1.1920929e-07f

typedef float  f32x4  __attribute__((ext_vector_type(4)));
typedef __bf16 bf16x8 __attribute__((ext_vector_type(8)));

__device__ __forceinline__ unsigned short f32_to_bf16(float f) {
    unsigned int u = __builtin_bit_cast(unsigned int, f);
    u += 0x7fffu + ((u >> 16) & 1u);   // round-to-nearest-even
    return (unsigned short)(u >> 16);
}

__device__ __forceinline__ float4 mix3(float a, const float4& u, float b,
                                       const float4& v, float c, const float4& w) {
    return make_float4(a * u.x + b * v.x + c * w.x,
                       a * u.y + b * v.y + c * w.y,
                       a * u.z + b * v.z + c * w.z,
                       a * u.w + b * v.w + c * w.w);
}

// ============ per-cycle kernel: block owns tokens 4b..4b+3 =================
// c==0: embed-gather fused (reads table rows incl. halos)
// c==7: final out-RMSNorm + bf16 cast fused (writes xbf, skips xout)
// every launch also converts a 1/8 slice of lm_head fp32->bf16.
__global__ __launch_bounds__(256) void k_cyc(
    int c,
    const int* __restrict__ tokens, const float* __restrict__ table,
    const float* __restrict__ xin, float* __restrict__ xout,
    const float* __restrict__ angles, const float* __restrict__ scales,
    const float* __restrict__ shifts, const float* __restrict__ normw,
    const float* __restrict__ mixw, const float* __restrict__ outnw,
    unsigned short* __restrict__ xbf,
    const int* __restrict__ pi, const int* __restrict__ pj,
    const float* __restrict__ lmhead, unsigned short* __restrict__ wbf)
{
    __shared__ float lx[4][D_DIM];
    __shared__ float red[4][4];   // [wave][token]
    const int b = blockIdx.x, tid = threadIdx.x;
    const int wv = tid >> 6, ln = tid & 63;
    const int t0 = b << 2;
    const int s0 = t0 & (S_LEN - 1);

    float4 row[4];
    float4 hl = make_float4(0.f, 0.f, 0.f, 0.f);
    float4 hr = make_float4(0.f, 0.f, 0.f, 0.f);
    if (c == 0) {
        #pragma unroll
        for (int i = 0; i < 4; ++i) {
            const int tok = tokens[t0 + i];
            row[i] = ((const float4*)(table + (size_t)tok * D_DIM))[tid];
        }
        if (s0 > 0) {
            const int tok = tokens[t0 - 1];
            hl = ((const float4*)(table + (size_t)tok * D_DIM))[tid];
        }
        if (s0 + 4 < S_LEN) {
            const int tok = tokens[t0 + 4];
            hr = ((const float4*)(table + (size_t)tok * D_DIM))[tid];
        }
    } else {
        #pragma unroll
        for (int i = 0; i < 4; ++i)
            row[i] = ((const float4*)(xin + (size_t)(t0 + i) * D_DIM))[tid];
        if (s0 > 0)
            hl = ((const float4*)(xin + (size_t)(t0 - 1) * D_DIM))[tid];
        if (s0 + 4 < S_LEN)
            hr = ((const float4*)(xin + (size_t)(t0 + 4) * D_DIM))[tid];
    }
    const float mw0 = mixw[0], mw1 = mixw[1], mw2 = mixw[2];

    // temporal mix
    float4 m[4];
    m[0] = mix3(mw0, hl,     mw1, row[0], mw2, row[1]);
    m[1] = mix3(mw0, row[0], mw1, row[1], mw2, row[2]);
    m[2] = mix3(mw0, row[1], mw1, row[2], mw2, row[3]);
    m[3] = mix3(mw0, row[2], mw1, row[3], mw2, hr);
    #pragma unroll
    for (int i = 0; i < 4; ++i) ((float4*)lx[i])[tid] = m[i];
    __syncthreads();

    // Givens rotation: thread tid owns plane pair (pi[tid], pj[tid]); pairs
    // are disjoint across threads -> thread-local read+write, no barrier.
    const int ip = pi[tid], jp = pj[tid];
    float sa, ca;
    sincosf(angles[tid], &sa, &ca);
    float xi[4], xj[4];
    #pragma unroll
    for (int i = 0; i < 4; ++i) { xi[i] = lx[i][ip]; xj[i] = lx[i][jp]; }
    #pragma unroll
    for (int i = 0; i < 4; ++i) {
        lx[i][ip] = xi[i] * ca - xj[i] * sa;
        lx[i][jp] = xi[i] * sa + xj[i] * ca;
    }
    __syncthreads();

    // scale/shift + SiLU, residual RMSNorm
    const float4 sc = ((const float4*)scales)[tid];
    const float4 sh = ((const float4*)shifts)[tid];
    const float4 nw = ((const float4*)normw)[tid];
    float4 r[4];
    float sum[4];
    #pragma unroll
    for (int i = 0; i < 4; ++i) {
        const float4 xn = ((const float4*)lx[i])[tid];
        const float a0 = xn.x * sc.x + sh.x;
        const float a1 = xn.y * sc.y + sh.y;
        const float a2 = xn.z * sc.z + sh.z;
        const float a3 = xn.w * sc.w + sh.w;
        r[i].x = a0 / (1.f + expf(-a0)) - m[i].x;
        r[i].y = a1 / (1.f + expf(-a1)) - m[i].y;
        r[i].z = a2 / (1.f + expf(-a2)) - m[i].z;
        r[i].w = a3 / (1.f + expf(-a3)) - m[i].w;
        sum[i] = r[i].x * r[i].x + r[i].y * r[i].y
               + r[i].z * r[i].z + r[i].w * r[i].w;
    }
    #pragma unroll
    for (int off = 32; off > 0; off >>= 1)
        #pragma unroll
        for (int i = 0; i < 4; ++i) sum[i] += __shfl_down(sum[i], off, 64);
    if (ln == 0) {
        red[wv][0] = sum[0]; red[wv][1] = sum[1];
        red[wv][2] = sum[2]; red[wv][3] = sum[3];
    }
    __syncthreads();
    #pragma unroll
    for (int i = 0; i < 4; ++i) {
        const float tot = red[0][i] + red[1][i] + red[2][i] + red[3][i];
        const float inv = rsqrtf(tot * (1.0f / D_DIM) + EPS_F);
        row[i].x = m[i].x + r[i].x * inv * nw.x;
        row[i].y = m[i].y + r[i].y * inv * nw.y;
        row[i].z = m[i].z + r[i].z * inv * nw.z;
        row[i].w = m[i].w + r[i].w * inv * nw.w;
    }

    if (c == 7) {
        // final RMSNorm + bf16 cast
        __syncthreads();   // protect red reuse
        float fs[4];
        #pragma unroll
        for (int i = 0; i < 4; ++i)
            fs[i] = row[i].x * row[i].x + row[i].y * row[i].y
                  + row[i].z * row[i].z + row[i].w * row[i].w;
        #pragma unroll
        for (int off = 32; off > 0; off >>= 1)
            #pragma unroll
            for (int i = 0; i < 4; ++i) fs[i] += __shfl_down(fs[i], off, 64);
        if (ln == 0) {
            red[wv][0] = fs[0]; red[wv][1] = fs[1];
            red[wv][2] = fs[2]; red[wv][3] = fs[3];
        }
        __syncthreads();
        const float4 w = ((const float4*)outnw)[tid];
        #pragma unroll
        for (int i = 0; i < 4; ++i) {
            const float tot = red[0][i] + red[1][i] + red[2][i] + red[3][i];
            const float inv = rsqrtf(tot * (1.0f / D_DIM) + EPS_F);
            const ushort4 o = make_ushort4(f32_to_bf16(row[i].x * inv * w.x),
                                           f32_to_bf16(row[i].y * inv * w.y),
                                           f32_to_bf16(row[i].z * inv * w.z),
                                           f32_to_bf16(row[i].w * inv * w.w));
            ((ushort4*)xbf)[(size_t)(t0 + i) * 256 + tid] = o;
        }
    } else {
        #pragma unroll
        for (int i = 0; i < 4; ++i)
            ((float4*)(xout + (size_t)(t0 + i) * D_DIM))[tid] = row[i];
    }

    // lm_head fp32->bf16 slice for this cycle (1/8 of 8.192M float4s)
    {
        const int end = (c + 1) * 1024000;
        for (int i = c * 1024000 + b * 256 + tid; i < end; i += 262144) {
            const float4 v = ((const float4*)lmhead)[i];
            const ushort4 o = make_ushort4(f32_to_bf16(v.x), f32_to_bf16(v.y),
                                           f32_to_bf16(v.z), f32_to_bf16(v.w));
            ((ushort4*)wbf)[i] = o;
        }
    }
}

// ================= GEMM: 256x256 tile, BK=64, 8-phase schedule =============
#define GLD_LDS(g, l)                                                          \
    __builtin_amdgcn_global_load_lds(                                          \
        (const __attribute__((address_space(1))) void*)(g),                    \
        (__attribute__((address_space(3))) void*)(l), 16, 0, 0)

#define STAGE_A(BUF, H, KT) do {                                               \
    GLD_LDS(gA + (size_t)(H) * 131072 + (size_t)(KT) * 64,                     \
            &lds[(BUF) * 32768 + (H) * 8192 + wave * 1024]);                   \
    GLD_LDS(gA + (size_t)(H) * 131072 + 8192 + (size_t)(KT) * 64,              \
            &lds[(BUF) * 32768 + (H) * 8192 + wave * 1024 + 512]);             \
} while (0)

#define STAGE_B(BUF, H, KT) do {                                               \
    GLD_LDS(gB + (size_t)(H) * 131072 + (size_t)(KT) * 64,                     \
            &lds[16384 + (BUF) * 32768 + (H) * 8192 + wave * 1024]);           \
    GLD_LDS(gB + (size_t)(H) * 131072 + 8192 + (size_t)(KT) * 64,              \
            &lds[16384 + (BUF) * 32768 + (H) * 8192 + wave * 1024 + 512]);     \
} while (0)

#define RD_A(BUF, MIB) do { _Pragma("unroll")                                  \
    for (int q_ = 0; q_ < 4; ++q_) {                                           \
        afr[q_][0] = *(const bf16x8*)&lds[(BUF) * 32768 + aoff + ((MIB) + q_) * 1024 + kx0]; \
        afr[q_][1] = *(const bf16x8*)&lds[(BUF) * 32768 + aoff + ((MIB) + q_) * 1024 + kx1]; \
    } } while (0)

#define RD_B(BUF, NIB, DST) do { _Pragma("unroll")                             \
    for (int n_ = 0; n_ < 2; ++n_) {                                           \
        DST[n_][0] = *(const bf16x8*)&lds[(BUF) * 32768 + boff + ((NIB) + n_) * 1024 + kx0]; \
        DST[n_][1] = *(const bf16x8*)&lds[(BUF) * 32768 + boff + ((NIB) + n_) * 1024 + kx1]; \
    } } while (0)

#define MFMA16(MIB, NIB, BF) do {                                              \
    __builtin_amdgcn_s_setprio(1);                                             \
    _Pragma("unroll") for (int m_ = 0; m_ < 4; ++m_)                           \
    _Pragma("unroll") for (int n_ = 0; n_ < 2; ++n_) {                         \
        acc[(MIB) + m_][(NIB) + n_] = __builtin_amdgcn_mfma_f32_16x16x32_bf16( \
            afr[m_][0], BF[n_][0], acc[(MIB) + m_][(NIB) + n_], 0, 0, 0);      \
        acc[(MIB) + m_][(NIB) + n_] = __builtin_amdgcn_mfma_f32_16x16x32_bf16( \
            afr[m_][1], BF[n_][1], acc[(MIB) + m_][(NIB) + n_], 0, 0, 0);      \
    }                                                                          \
    __builtin_amdgcn_s_setprio(0); } while (0)

#define PH_SYNC() do { __builtin_amdgcn_s_barrier();                           \
    asm volatile("s_waitcnt lgkmcnt(0)" ::: "memory"); } while (0)
#define PH_END() do { asm volatile("" ::: "memory");                           \
    __builtin_amdgcn_s_barrier(); } while (0)
#define VMCNT4() asm volatile("s_waitcnt vmcnt(4)" ::: "memory")

__global__ __launch_bounds__(512, 2) void k_gemm(
    const unsigned short* __restrict__ A,   // [NTOK, 1024] bf16 bits
    const unsigned short* __restrict__ Bw,  // [V, 1024]    bf16 bits
    float* __restrict__ C)                  // [NTOK, V]    fp32
{
    __shared__ __align__(16) unsigned short lds[65536];   // 128 KiB
    const int tid = threadIdx.x;
    const int wave = tid >> 6, lane = tid & 63;
    const int wm = wave >> 2, wn = wave & 3;
    const int lr = lane & 15, kg = lane >> 4;

    // XCD-chunked swizzle (2000 % 8 == 0 -> bijective), then bm-fastest
    // within a chunk so 16 consecutive same-XCD blocks share one B panel
    // (B panel lives in that XCD's L2; working set ~2 MB < 4 MB).
    const int swz = (blockIdx.x & 7) * 250 + (blockIdx.x >> 3);
    const int bm = swz & 15, bn = swz >> 4;

    const int xr  = (lane & 7) * 8;
    const int kx0 = (kg * 8) ^ xr;
    const int kx1 = (32 + kg * 8) ^ xr;
    const int aoff = (wm * 128 + lr) * 64;
    const int boff = 16384 + (wn * 64 + lr) * 64;

    const int srow = lane >> 3;
    const int scol = ((lane & 7) ^ srow) * 8;
    const unsigned short* gA = A  + (size_t)(bm * 256 + wave * 16 + srow) * 1024 + scol;
    const unsigned short* gB = Bw + (size_t)(bn * 256 + wave * 16 + srow) * 1024 + scol;

    f32x4 acc[8][4];
    #pragma unroll
    for (int i = 0; i < 8; ++i)
        #pragma unroll
        for (int j = 0; j < 4; ++j) acc[i][j] = (f32x4){0.f, 0.f, 0.f, 0.f};
    bf16x8 afr[4][2], b01[2][2], b23[2][2];

    STAGE_A(0, 0, 0); STAGE_A(0, 1, 0);
    STAGE_B(0, 0, 0); STAGE_B(0, 1, 0);
    STAGE_B(1, 0, 1); STAGE_B(1, 1, 1);
    VMCNT4();
    __builtin_amdgcn_s_barrier();

    for (int j = 0; j < 8; ++j) {
        const int k1 = (2 * j + 1) & 15;
        const int k2 = (2 * j + 2) & 15;
        const int k3 = (2 * j + 3) & 15;

        RD_A(0, 0); RD_B(0, 0, b01);
        STAGE_A(1, 0, k1);
        PH_SYNC(); MFMA16(0, 0, b01); PH_END();

        RD_B(0, 2, b23);
        STAGE_A(1, 1, k1);
        PH_SYNC(); MFMA16(0, 2, b23); PH_END();

        RD_A(0, 4);
        STAGE_B(0, 0, k2);
        PH_SYNC(); MFMA16(4, 2, b23); PH_END();

        STAGE_B(0, 1, k2);
        VMCNT4();
        PH_SYNC(); MFMA16(4, 0, b01); PH_END();

        RD_A(1, 0); RD_B(1, 0, b01);
        STAGE_A(0, 0, k2);
        PH_SYNC(); MFMA16(0, 0, b01); PH_END();

        RD_B(1, 2, b23);
        STAGE_A(0, 1, k2);
        PH_SYNC(); MFMA16(0, 2, b23); PH_END();

        RD_A(1, 4);
        STAGE_B(1, 0, k3);
        PH_SYNC(); MFMA16(4, 2, b23); PH_END();

        STAGE_B(1, 1, k3);
        VMCNT4();
        PH_SYNC(); MFMA16(4, 0, b01); PH_END();
    }

    // epilogue: nontemporal C stores (keep B panels cache-resident)
    #pragma unroll
    for (int mi = 0; mi < 8; ++mi) {
        const size_t m0 = (size_t)(bm * 256 + wm * 128 + mi * 16 + kg * 4);
        #pragma unroll
        for (int ni = 0; ni < 4; ++ni) {
            const int n = bn * 256 + wn * 64 + ni * 16 + lr;
            float* cp = C + m0 * V_DIM + n;
            __builtin_nontemporal_store(acc[mi][ni][0], cp);
            __builtin_nontemporal_store(acc[mi][ni][1], cp + (size_t)V_DIM);
            __builtin_nontemporal_store(acc[mi][ni][2], cp + (size_t)2 * V_DIM);
            __builtin_nontemporal_store(acc[mi][ni][3], cp + (size_t)3 * V_DIM);
        }
    }
}

extern "C" void kernel_launch(void* const* d_in, const int* in_sizes, int n_in,
                              void* d_out, int out_size, void* d_ws, size_t ws_size,
                              hipStream_t stream)
{
    const int*   tokens = (const int*)  d_in[0];
    const float* embedw = (const float*)d_in[1];
    const float* angles = (const float*)d_in[2];
    const float* scales = (const float*)d_in[3];
    const float* shifts = (const float*)d_in[4];
    const float* normw  = (const float*)d_in[5];
    const float* mixw   = (const float*)d_in[6];
    const float* outnw  = (const float*)d_in[7];
    const float* lmhead = (const float*)d_in[8];
    const int*   pi_all = (const int*)  d_in[9];
    const int*   pj_all = (const int*)  d_in[10];
    float* out = (float*)d_out;

    float* xa = (float*)d_ws;
    float* xb = xa + (size_t)NTOK * D_DIM;
    unsigned short* xbf = (unsigned short*)(xb + (size_t)NTOK * D_DIM);
    unsigned short* wbf = xbf + (size_t)NTOK * D_DIM;

    // cycle c: c==0 gathers from table (xin unused); c odd reads xb writes xa;
    // c even reads xa writes xb; c==7 writes xbf (bf16) instead of xout.
    for (int c = 0; c < NCYC; ++c) {
        const float* xin = (c & 1) ? xb : xa;
        float* xout = (c & 1) ? xa : xb;
        k_cyc<<<NTOK / 4, 256, 0, stream>>>(c, tokens, embedw, xin, xout,
            angles + c * NPLANES, scales + c * D_DIM, shifts + c * D_DIM,
            normw + c * D_DIM, mixw, outnw, xbf,
            pi_all + c * NPLANES, pj_all + c * NPLANES, lmhead, wbf);
    }

    k_gemm<<<16 * 125, 512, 0, stream>>>(xbf, wbf, out);
}

// Round 5
// 422.222 us; speedup vs baseline: 1.5461x; 1.0084x over previous
//
#include <hip/hip_runtime.h>

#define B_SZ   2
#define S_LEN  2048
#define D_DIM  1024
#define V_DIM  32000
#define NTOK   (B_SZ * S_LEN)   // 4096
#define NCYC   8
#define NPLANES 256
#define EPS_F  1.1920929e-07f
#define NTILE  2000             // 16 bm x 125 bn

typedef float  f32x4  __attribute__((ext_vector_type(4)));
typedef __bf16 bf16x8 __attribute__((ext_vector_type(8)));

__device__ __forceinline__ unsigned short f32_to_bf16(float f) {
    unsigned int u = __builtin_bit_cast(unsigned int, f);
    u += 0x7fffu + ((u >> 16) & 1u);   // round-to-nearest-even
    return (unsigned short)(u >> 16);
}

__device__ __forceinline__ float4 mix3(float a, const float4& u, float b,
                                       const float4& v, float c, const float4& w) {
    return make_float4(a * u.x + b * v.x + c * w.x,
                       a * u.y + b * v.y + c * w.y,
                       a * u.z + b * v.z + c * w.z,
                       a * u.w + b * v.w + c * w.w);
}

// ============ per-cycle kernel: block owns tokens 4b..4b+3 =================
__global__ __launch_bounds__(256) void k_cyc(
    int c,
    const int* __restrict__ tokens, const float* __restrict__ table,
    const float* __restrict__ xin, float* __restrict__ xout,
    const float* __restrict__ angles, const float* __restrict__ scales,
    const float* __restrict__ shifts, const float* __restrict__ normw,
    const float* __restrict__ mixw, const float* __restrict__ outnw,
    unsigned short* __restrict__ xbf,
    const int* __restrict__ pi, const int* __restrict__ pj,
    const float* __restrict__ lmhead, unsigned short* __restrict__ wbf)
{
    __shared__ float lx[4][D_DIM];
    __shared__ float red[4][4];   // [wave][token]
    const int b = blockIdx.x, tid = threadIdx.x;
    const int wv = tid >> 6, ln = tid & 63;
    const int t0 = b << 2;
    const int s0 = t0 & (S_LEN - 1);

    float4 row[4];
    float4 hl = make_float4(0.f, 0.f, 0.f, 0.f);
    float4 hr = make_float4(0.f, 0.f, 0.f, 0.f);
    if (c == 0) {
        #pragma unroll
        for (int i = 0; i < 4; ++i) {
            const int tok = tokens[t0 + i];
            row[i] = ((const float4*)(table + (size_t)tok * D_DIM))[tid];
        }
        if (s0 > 0) {
            const int tok = tokens[t0 - 1];
            hl = ((const float4*)(table + (size_t)tok * D_DIM))[tid];
        }
        if (s0 + 4 < S_LEN) {
            const int tok = tokens[t0 + 4];
            hr = ((const float4*)(table + (size_t)tok * D_DIM))[tid];
        }
    } else {
        #pragma unroll
        for (int i = 0; i < 4; ++i)
            row[i] = ((const float4*)(xin + (size_t)(t0 + i) * D_DIM))[tid];
        if (s0 > 0)
            hl = ((const float4*)(xin + (size_t)(t0 - 1) * D_DIM))[tid];
        if (s0 + 4 < S_LEN)
            hr = ((const float4*)(xin + (size_t)(t0 + 4) * D_DIM))[tid];
    }
    const float mw0 = mixw[0], mw1 = mixw[1], mw2 = mixw[2];

    float4 m[4];
    m[0] = mix3(mw0, hl,     mw1, row[0], mw2, row[1]);
    m[1] = mix3(mw0, row[0], mw1, row[1], mw2, row[2]);
    m[2] = mix3(mw0, row[1], mw1, row[2], mw2, row[3]);
    m[3] = mix3(mw0, row[2], mw1, row[3], mw2, hr);
    #pragma unroll
    for (int i = 0; i < 4; ++i) ((float4*)lx[i])[tid] = m[i];
    __syncthreads();

    const int ip = pi[tid], jp = pj[tid];
    float sa, ca;
    sincosf(angles[tid], &sa, &ca);
    float xi[4], xj[4];
    #pragma unroll
    for (int i = 0; i < 4; ++i) { xi[i] = lx[i][ip]; xj[i] = lx[i][jp]; }
    #pragma unroll
    for (int i = 0; i < 4; ++i) {
        lx[i][ip] = xi[i] * ca - xj[i] * sa;
        lx[i][jp] = xi[i] * sa + xj[i] * ca;
    }
    __syncthreads();

    const float4 sc = ((const float4*)scales)[tid];
    const float4 sh = ((const float4*)shifts)[tid];
    const float4 nw = ((const float4*)normw)[tid];
    float4 r[4];
    float sum[4];
    #pragma unroll
    for (int i = 0; i < 4; ++i) {
        const float4 xn = ((const float4*)lx[i])[tid];
        const float a0 = xn.x * sc.x + sh.x;
        const float a1 = xn.y * sc.y + sh.y;
        const float a2 = xn.z * sc.z + sh.z;
        const float a3 = xn.w * sc.w + sh.w;
        r[i].x = a0 / (1.f + expf(-a0)) - m[i].x;
        r[i].y = a1 / (1.f + expf(-a1)) - m[i].y;
        r[i].z = a2 / (1.f + expf(-a2)) - m[i].z;
        r[i].w = a3 / (1.f + expf(-a3)) - m[i].w;
        sum[i] = r[i].x * r[i].x + r[i].y * r[i].y
               + r[i].z * r[i].z + r[i].w * r[i].w;
    }
    #pragma unroll
    for (int off = 32; off > 0; off >>= 1)
        #pragma unroll
        for (int i = 0; i < 4; ++i) sum[i] += __shfl_down(sum[i], off, 64);
    if (ln == 0) {
        red[wv][0] = sum[0]; red[wv][1] = sum[1];
        red[wv][2] = sum[2]; red[wv][3] = sum[3];
    }
    __syncthreads();
    #pragma unroll
    for (int i = 0; i < 4; ++i) {
        const float tot = red[0][i] + red[1][i] + red[2][i] + red[3][i];
        const float inv = rsqrtf(tot * (1.0f / D_DIM) + EPS_F);
        row[i].x = m[i].x + r[i].x * inv * nw.x;
        row[i].y = m[i].y + r[i].y * inv * nw.y;
        row[i].z = m[i].z + r[i].z * inv * nw.z;
        row[i].w = m[i].w + r[i].w * inv * nw.w;
    }

    if (c == 7) {
        __syncthreads();
        float fs[4];
        #pragma unroll
        for (int i = 0; i < 4; ++i)
            fs[i] = row[i].x * row[i].x + row[i].y * row[i].y
                  + row[i].z * row[i].z + row[i].w * row[i].w;
        #pragma unroll
        for (int off = 32; off > 0; off >>= 1)
            #pragma unroll
            for (int i = 0; i < 4; ++i) fs[i] += __shfl_down(fs[i], off, 64);
        if (ln == 0) {
            red[wv][0] = fs[0]; red[wv][1] = fs[1];
            red[wv][2] = fs[2]; red[wv][3] = fs[3];
        }
        __syncthreads();
        const float4 w = ((const float4*)outnw)[tid];
        #pragma unroll
        for (int i = 0; i < 4; ++i) {
            const float tot = red[0][i] + red[1][i] + red[2][i] + red[3][i];
            const float inv = rsqrtf(tot * (1.0f / D_DIM) + EPS_F);
            const ushort4 o = make_ushort4(f32_to_bf16(row[i].x * inv * w.x),
                                           f32_to_bf16(row[i].y * inv * w.y),
                                           f32_to_bf16(row[i].z * inv * w.z),
                                           f32_to_bf16(row[i].w * inv * w.w));
            ((ushort4*)xbf)[(size_t)(t0 + i) * 256 + tid] = o;
        }
    } else {
        #pragma unroll
        for (int i = 0; i < 4; ++i)
            ((float4*)(xout + (size_t)(t0 + i) * D_DIM))[tid] = row[i];
    }

    // lm_head fp32->bf16 slice for this cycle
    {
        const int end = (c + 1) * 1024000;
        for (int i = c * 1024000 + b * 256 + tid; i < end; i += 262144) {
            const float4 v = ((const float4*)lmhead)[i];
            const ushort4 o = make_ushort4(f32_to_bf16(v.x), f32_to_bf16(v.y),
                                           f32_to_bf16(v.z), f32_to_bf16(v.w));
            ((ushort4*)wbf)[i] = o;
        }
    }
}

// ====== persistent GEMM: 256x256 tile, BK=64, 8-phase, cross-tile seam =====
// 256 blocks; block bid does tiles g = bid, bid+256, ... (7-8 tiles).
// At j==7 the k2/k3 stages (which wrap to ktile 0/1) use the NEXT tile's
// base pointers = the prologue of the next tile, for free. Epilogue stores
// are plain dwords issued between tiles; the next tile's phase-4 vmcnt(4)
// drains them (L2 ack) overlapped with phases 1-3 MFMA.
#define GLD_LDS(g, l)                                                          \
    __builtin_amdgcn_global_load_lds(                                          \
        (const __attribute__((address_space(1))) void*)(g),                    \
        (__attribute__((address_space(3))) void*)(l), 16, 0, 0)

#define STAGE_A(BUF, H, KT, P) do {                                            \
    GLD_LDS((P) + (size_t)(H) * 131072 + (size_t)(KT) * 64,                    \
            &lds[(BUF) * 32768 + (H) * 8192 + wave * 1024]);                   \
    GLD_LDS((P) + (size_t)(H) * 131072 + 8192 + (size_t)(KT) * 64,             \
            &lds[(BUF) * 32768 + (H) * 8192 + wave * 1024 + 512]);             \
} while (0)

#define STAGE_B(BUF, H, KT, P) do {                                            \
    GLD_LDS((P) + (size_t)(H) * 131072 + (size_t)(KT) * 64,                    \
            &lds[16384 + (BUF) * 32768 + (H) * 8192 + wave * 1024]);           \
    GLD_LDS((P) + (size_t)(H) * 131072 + 8192 + (size_t)(KT) * 64,             \
            &lds[16384 + (BUF) * 32768 + (H) * 8192 + wave * 1024 + 512]);     \
} while (0)

#define RD_A(BUF, MIB) do { _Pragma("unroll")                                  \
    for (int q_ = 0; q_ < 4; ++q_) {                                           \
        afr[q_][0] = *(const bf16x8*)&lds[(BUF) * 32768 + aoff + ((MIB) + q_) * 1024 + kx0]; \
        afr[q_][1] = *(const bf16x8*)&lds[(BUF) * 32768 + aoff + ((MIB) + q_) * 1024 + kx1]; \
    } } while (0)

#define RD_B(BUF, NIB, DST) do { _Pragma("unroll")                             \
    for (int n_ = 0; n_ < 2; ++n_) {                                           \
        DST[n_][0] = *(const bf16x8*)&lds[(BUF) * 32768 + boff + ((NIB) + n_) * 1024 + kx0]; \
        DST[n_][1] = *(const bf16x8*)&lds[(BUF) * 32768 + boff + ((NIB) + n_) * 1024 + kx1]; \
    } } while (0)

#define MFMA16(MIB, NIB, BF) do {                                              \
    __builtin_amdgcn_s_setprio(1);                                             \
    _Pragma("unroll") for (int m_ = 0; m_ < 4; ++m_)                           \
    _Pragma("unroll") for (int n_ = 0; n_ < 2; ++n_) {                         \
        acc[(MIB) + m_][(NIB) + n_] = __builtin_amdgcn_mfma_f32_16x16x32_bf16( \
            afr[m_][0], BF[n_][0], acc[(MIB) + m_][(NIB) + n_], 0, 0, 0);      \
        acc[(MIB) + m_][(NIB) + n_] = __builtin_amdgcn_mfma_f32_16x16x32_bf16( \
            afr[m_][1], BF[n_][1], acc[(MIB) + m_][(NIB) + n_], 0, 0, 0);      \
    }                                                                          \
    __builtin_amdgcn_s_setprio(0); } while (0)

#define PH_SYNC() do { __builtin_amdgcn_s_barrier();                           \
    asm volatile("s_waitcnt lgkmcnt(0)" ::: "memory"); } while (0)
#define PH_END() do { asm volatile("" ::: "memory");                           \
    __builtin_amdgcn_s_barrier(); } while (0)
#define VMCNT4() asm volatile("s_waitcnt vmcnt(4)" ::: "memory")

__global__ __launch_bounds__(512, 2) void k_gemm(
    const unsigned short* __restrict__ A,   // [NTOK, 1024] bf16 bits
    const unsigned short* __restrict__ Bw,  // [V, 1024]    bf16 bits
    float* __restrict__ C)                  // [NTOK, V]    fp32
{
    __shared__ __align__(16) unsigned short lds[65536];   // 128 KiB
    const int tid = threadIdx.x;
    const int wave = tid >> 6, lane = tid & 63;
    const int wm = wave >> 2, wn = wave & 3;
    const int lr = lane & 15, kg = lane >> 4;

    const int xr  = (lane & 7) * 8;
    const int kx0 = (kg * 8) ^ xr;
    const int kx1 = (32 + kg * 8) ^ xr;
    const int aoff = (wm * 128 + lr) * 64;
    const int boff = 16384 + (wn * 64 + lr) * 64;

    const int srow = lane >> 3;
    const int scol = ((lane & 7) ^ srow) * 8;   // pre-swizzled source col
    const int soff = (wave * 16 + srow) * 1024 + scol;

    int g  = blockIdx.x;                 // tile id: bm = g&15, bn = g>>4
    int bm = g & 15, bn = g >> 4;
    const unsigned short* gA = A  + (size_t)(bm * 256) * 1024 + soff;
    const unsigned short* gB = Bw + (size_t)(bn * 256) * 1024 + soff;

    bf16x8 afr[4][2], b01[2][2], b23[2][2];

    // prologue (once per block)
    STAGE_A(0, 0, 0, gA); STAGE_A(0, 1, 0, gA);
    STAGE_B(0, 0, 0, gB); STAGE_B(0, 1, 0, gB);
    STAGE_B(1, 0, 1, gB); STAGE_B(1, 1, 1, gB);
    VMCNT4();
    __builtin_amdgcn_s_barrier();

    while (true) {
        const int gn_raw = g + 256;
        const bool last = (gn_raw >= NTILE);
        const int gn = last ? g : gn_raw;          // clamp: redundant restage
        const int bm2 = gn & 15, bn2 = gn >> 4;
        const unsigned short* gA2 = A  + (size_t)(bm2 * 256) * 1024 + soff;
        const unsigned short* gB2 = Bw + (size_t)(bn2 * 256) * 1024 + soff;

        f32x4 acc[8][4];
        #pragma unroll
        for (int i = 0; i < 8; ++i)
            #pragma unroll
            for (int j2 = 0; j2 < 4; ++j2) acc[i][j2] = (f32x4){0.f, 0.f, 0.f, 0.f};

        for (int j = 0; j < 8; ++j) {
            const unsigned short* sA = (j == 7) ? gA2 : gA;
            const unsigned short* sB = (j == 7) ? gB2 : gB;
            const int k1 = 2 * j + 1;          // current tile, <=15
            const int k2 = (2 * j + 2) & 15;   // wraps to 0 at j==7 (next tile)
            const int k3 = (2 * j + 3) & 15;   // wraps to 1 at j==7 (next tile)

            RD_A(0, 0); RD_B(0, 0, b01);
            STAGE_A(1, 0, k1, gA);
            PH_SYNC(); MFMA16(0, 0, b01); PH_END();

            RD_B(0, 2, b23);
            STAGE_A(1, 1, k1, gA);
            PH_SYNC(); MFMA16(0, 2, b23); PH_END();

            RD_A(0, 4);
            STAGE_B(0, 0, k2, sB);
            PH_SYNC(); MFMA16(4, 2, b23); PH_END();

            STAGE_B(0, 1, k2, sB);
            VMCNT4();
            PH_SYNC(); MFMA16(4, 0, b01); PH_END();

            RD_A(1, 0); RD_B(1, 0, b01);
            STAGE_A(0, 0, k2, sA);
            PH_SYNC(); MFMA16(0, 0, b01); PH_END();

            RD_B(1, 2, b23);
            STAGE_A(0, 1, k2, sA);
            PH_SYNC(); MFMA16(0, 2, b23); PH_END();

            RD_A(1, 4);
            STAGE_B(1, 0, k3, sB);
            PH_SYNC(); MFMA16(4, 2, b23); PH_END();

            STAGE_B(1, 1, k3, sB);
            VMCNT4();
            PH_SYNC(); MFMA16(4, 0, b01); PH_END();
        }

        // epilogue: plain stores (L2-merged, WRITE_SIZE exact; round-1 data)
        #pragma unroll
        for (int mi = 0; mi < 8; ++mi) {
            const size_t m0 = (size_t)(bm * 256 + wm * 128 + mi * 16 + kg * 4);
            #pragma unroll
            for (int ni = 0; ni < 4; ++ni) {
                const int n = bn * 256 + wn * 64 + ni * 16 + lr;
                float* cp = C + m0 * V_DIM + n;
                cp[0]                 = acc[mi][ni][0];
                cp[(size_t)V_DIM]     = acc[mi][ni][1];
                cp[(size_t)2 * V_DIM] = acc[mi][ni][2];
                cp[(size_t)3 * V_DIM] = acc[mi][ni][3];
            }
        }

        if (last) break;
        g = gn; bm = bm2; bn = bn2; gA = gA2; gB = gB2;
    }
}

extern "C" void kernel_launch(void* const* d_in, const int* in_sizes, int n_in,
                              void* d_out, int out_size, void* d_ws, size_t ws_size,
                              hipStream_t stream)
{
    const int*   tokens = (const int*)  d_in[0];
    const float* embedw = (const float*)d_in[1];
    const float* angles = (const float*)d_in[2];
    const float* scales = (const float*)d_in[3];
    const float* shifts = (const float*)d_in[4];
    const float* normw  = (const float*)d_in[5];
    const float* mixw   = (const float*)d_in[6];
    const float* outnw  = (const float*)d_in[7];
    const float* lmhead = (const float*)d_in[8];
    const int*   pi_all = (const int*)  d_in[9];
    const int*   pj_all = (const int*)  d_in[10];
    float* out = (float*)d_out;

    float* xa = (float*)d_ws;
    float* xb = xa + (size_t)NTOK * D_DIM;
    unsigned short* xbf = (unsigned short*)(xb + (size_t)NTOK * D_DIM);
    unsigned short* wbf = xbf + (size_t)NTOK * D_DIM;

    for (int c = 0; c < NCYC; ++c) {
        const float* xin = (c & 1) ? xb : xa;
        float* xout = (c & 1) ? xa : xb;
        k_cyc<<<NTOK / 4, 256, 0, stream>>>(c, tokens, embedw, xin, xout,
            angles + c * NPLANES, scales + c * D_DIM, shifts + c * D_DIM,
            normw + c * D_DIM, mixw, outnw, xbf,
            pi_all + c * NPLANES, pj_all + c * NPLANES, lmhead, wbf);
    }

    k_gemm<<<256, 512, 0, stream>>>(xbf, wbf, out);
}